// Round 3
// baseline (719.418 us; speedup 1.0000x reference)
//
#include <hip/hip_runtime.h>
#include <hip/hip_bf16.h>
#include <math.h>

#define EPSF 1e-5f

typedef __attribute__((ext_vector_type(4))) float f32x4;
typedef __attribute__((ext_vector_type(8))) short s16x8;

// ---------- block reduction (256 threads = 4 waves) ----------
__device__ __forceinline__ float block_reduce_sum_256(float s) {
  #pragma unroll
  for (int o = 32; o > 0; o >>= 1) s += __shfl_xor(s, o, 64);
  __shared__ float red[4];
  int lane = threadIdx.x & 63, wid = threadIdx.x >> 6;
  if (lane == 0) red[wid] = s;
  __syncthreads();
  return red[0] + red[1] + red[2] + red[3];
}

// ---------- K0: h = expmap0(x) as bf16; cx2, 1/(1-cx2) per row ----------
__global__ void k_expmap(const float* __restrict__ x, __hip_bfloat16* __restrict__ h,
                         float* __restrict__ cx2, float* __restrict__ invomc, int K) {
  int row = blockIdx.x;
  const float* xr = x + (size_t)row * K;
  int t = threadIdx.x;
  float v[16];
  float s = 0.f;
  int nit = K >> 8;
  #pragma unroll
  for (int i = 0; i < 16; ++i) {
    if (i < nit) { v[i] = xr[t + (i << 8)]; s += v[i] * v[i]; }
  }
  float nsq = block_reduce_sum_256(s);
  float n = fmaxf(sqrtf(nsq), EPSF);
  float sc = tanhf(n) / n;            // rc = 1
  float hn2 = sc * sc * nsq;          // ||h||^2
  float c2 = fminf(hn2, 1.f - EPSF);
  if (t == 0) { cx2[row] = c2; invomc[row] = 1.f / (1.f - c2); }
  __hip_bfloat16* hr = h + (size_t)row * K;
  #pragma unroll
  for (int i = 0; i < 16; ++i) {
    if (i < nit) hr[t + (i << 8)] = __float2bfloat16(sc * v[i]);
  }
}

// ---------- K1a: partial column sum-of-squares of z (deterministic) ----------
__global__ void k_colsq(const float* __restrict__ z, float* __restrict__ part,
                        int K, int N, int rows_per_chunk) {
  int col = blockIdx.x * 256 + threadIdx.x;
  int r0 = blockIdx.y * rows_per_chunk;
  float s = 0.f;
  for (int r = r0; r < r0 + rows_per_chunk; ++r) {
    float v = z[(size_t)r * N + col];
    s += v * v;
  }
  part[(size_t)blockIdx.y * N + col] = s;
}

// ---------- K1b: finalize per-column scalars ----------
__global__ void k_colfin(const float* __restrict__ part, const float* __restrict__ bias,
                         float* __restrict__ zn2, float* __restrict__ invzn,
                         float* __restrict__ ch, float* __restrict__ sh,
                         int N, int nchunk) {
  int c = blockIdx.x * 256 + threadIdx.x;
  float s = 0.f;
  for (int i = 0; i < nchunk; ++i) s += part[(size_t)i * N + c];
  float zn = fmaxf(sqrtf(s), EPSF);
  zn2[c] = 2.f * zn;
  invzn[c] = 1.f / zn;
  float d = 2.f * bias[c];
  ch[c] = coshf(d);
  sh[c] = sinhf(d);
}

// ---------- K1c: z_unit^T (N x K) bf16, LDS tile transpose ----------
__global__ void k_zunitT(const float* __restrict__ z, const float* __restrict__ invzn,
                         __hip_bfloat16* __restrict__ zt, int K, int N) {
  __shared__ float tile[32][33];
  int tx = threadIdx.x, ty = threadIdx.y;   // (32,8)
  int c0 = blockIdx.x * 32, r0 = blockIdx.y * 32;
  float inv = invzn[c0 + tx];
  #pragma unroll
  for (int i = 0; i < 4; ++i)
    tile[ty + i * 8][tx] = z[(size_t)(r0 + ty + i * 8) * N + c0 + tx] * inv;
  __syncthreads();
  #pragma unroll
  for (int i = 0; i < 4; ++i)
    zt[(size_t)(c0 + ty + i * 8) * K + r0 + tx] = __float2bfloat16(tile[tx][ty + i * 8]);
}

// ---------- MFMA phase helper (compile-time quadrant) ----------
template<int MQ, int NQ>
__device__ __forceinline__ void mm_phase(f32x4 (&acc)[8][4], const s16x8 (&av)[4][2],
                                         const s16x8 (&bv)[4][2]) {
  #pragma unroll
  for (int i = 0; i < 4; ++i) {
    #pragma unroll
    for (int jn = 0; jn < 2; ++jn) {
      acc[MQ * 4 + i][NQ * 2 + jn] = __builtin_amdgcn_mfma_f32_16x16x32_bf16(
          av[i][0], bv[NQ * 2 + jn][0], acc[MQ * 4 + i][NQ * 2 + jn], 0, 0, 0);
      acc[MQ * 4 + i][NQ * 2 + jn] = __builtin_amdgcn_mfma_f32_16x16x32_bf16(
          av[i][1], bv[NQ * 2 + jn][1], acc[MQ * 4 + i][NQ * 2 + jn], 0, 0, 0);
    }
  }
}

// ---------- K2: 256x256 8-phase bf16 MFMA GEMM + Poincare-MLR epilogue ----------
// LDS layout (per dbuf d, 64KB): A halves at d*65536 + h*16384, B halves at +32768.
// Each 16KB half-tile = [128 rows][64 k] bf16 subtiled [rb=8][khalf=2][16][32] with
// st_16x32 swizzle: within-subtile byte ^= (row&8)<<2. global_load_lds writes
// LINEARLY (dest = tid*16 + j*8192); the SOURCE address is inverse-swizzled
// (rule #21), ds_reads apply the same swizzle.
// Staging schedule: tile kt+2 fully staged within kt: {B0@p1, B1@p2, A0+A1@p3};
// steady-state s_waitcnt vmcnt(8) at p3-end (the 8 loads of kt+2 stay in flight).
__global__ __launch_bounds__(512, 1) void k_gemm_epi(
    const __hip_bfloat16* __restrict__ A,   // h: M x K
    const __hip_bfloat16* __restrict__ Bt,  // z_unit^T: N x K
    const float* __restrict__ cx2, const float* __restrict__ invomc,
    const float* __restrict__ zn2, const float* __restrict__ ch,
    const float* __restrict__ sh,
    float* __restrict__ out, int M, int N, int K) {
  __shared__ __align__(16) char smem[131072];
  const int K2 = K * 2;
  int tid = threadIdx.x, lane = tid & 63, wid = tid >> 6;
  int wm = wid >> 2, wn = wid & 3;

  // bijective XCD swizzle (gridDim.x % 8 == 0 here: 512 blocks)
  int bid = blockIdx.x;
  int cpx = gridDim.x >> 3;
  int swz = (bid & 7) * cpx + (bid >> 3);
  int nbx = N >> 8;
  int bx = swz % nbx, by = swz / nbx;
  int bm0 = by * 256, bn0 = bx * 256;

  // ---- staging per-thread constants (inverse-swizzled global source) ----
  int rr = (tid >> 2) & 15;
  int cbyte = ((tid & 3) * 16) ^ ((rr & 8) << 2);
  int kb = ((tid >> 6) & 1) * 64 + cbyte;        // k-byte within tile [0,128)
  int r0 = ((tid >> 7) << 4) + rr;               // row for j=0; j=1 adds 64
  size_t pOff0 = (size_t)r0 * K2 + kb;
  size_t pOff1 = (size_t)(r0 + 64) * K2 + kb;
  int ldsW = wid * 1024;                          // linear dest slot (lane*16 implicit)

  const char* aPan0 = (const char*)A + (size_t)bm0 * K2;
  const char* aPan1 = aPan0 + (size_t)128 * K2;
  const char* bPan0 = (const char*)Bt + (size_t)bn0 * K2;
  const char* bPan1 = bPan0 + (size_t)128 * K2;

  // stage one half-tile (2 x global_load_lds, 16B/lane, linear LDS dest)
  auto STAGE = [&](const char* pan, int ldsBase, int ktOff) {
    __builtin_amdgcn_global_load_lds(
        (const __attribute__((address_space(1))) unsigned int*)(pan + ktOff + pOff0),
        (__attribute__((address_space(3))) unsigned int*)(smem + ldsBase + ldsW), 16, 0, 0);
    __builtin_amdgcn_global_load_lds(
        (const __attribute__((address_space(1))) unsigned int*)(pan + ktOff + pOff1),
        (__attribute__((address_space(3))) unsigned int*)(smem + ldsBase + ldsW + 8192), 16, 0, 0);
  };

  // ---- LDS read base (swizzled) ----
  int labase = (lane & 15) * 64 + (((lane >> 4) * 16) ^ ((lane & 8) << 2));

  s16x8 av[4][2], bv[4][2];
  f32x4 acc[8][4] = {};

  auto RDA = [&](int d, int mq) {
    const char* p = smem + d * 65536 + wm * 16384 + mq * 8192 + labase;
    #pragma unroll
    for (int i = 0; i < 4; ++i) {
      av[i][0] = *(const s16x8*)(p + i * 2048);
      av[i][1] = *(const s16x8*)(p + i * 2048 + 1024);
    }
  };
  auto RDB = [&](int d) {
    const char* p = smem + d * 65536 + 32768 + (wn >> 1) * 16384 + (wn & 1) * 8192 + labase;
    #pragma unroll
    for (int f = 0; f < 4; ++f) {
      bv[f][0] = *(const s16x8*)(p + f * 2048);
      bv[f][1] = *(const s16x8*)(p + f * 2048 + 1024);
    }
  };

  int NT = K >> 6;   // K-tiles of 64

  // ---- prologue: stage tile0 + tile1 fully (16 loads) ----
  STAGE(bPan0, 32768, 0);  STAGE(bPan1, 49152, 0);
  STAGE(aPan0, 0, 0);      STAGE(aPan1, 16384, 0);
  if (NT > 1) {
    STAGE(bPan0, 65536 + 32768, 128);  STAGE(bPan1, 65536 + 49152, 128);
    STAGE(aPan0, 65536, 128);          STAGE(aPan1, 65536 + 16384, 128);
    asm volatile("s_waitcnt vmcnt(8)" ::: "memory");
  } else {
    asm volatile("s_waitcnt vmcnt(0)" ::: "memory");
  }
  __builtin_amdgcn_sched_barrier(0);
  __builtin_amdgcn_s_barrier();

  for (int kt = 0; kt < NT; ++kt) {
    int d = kt & 1;
    int kOff2 = (kt + 2) << 7;
    bool pf = (kt + 2 < NT);
    // ---- phase 0: (mq0, nq0); read av-mq0 + all bv ----
    RDA(d, 0); RDB(d);
    __builtin_amdgcn_s_barrier();
    asm volatile("s_waitcnt lgkmcnt(0)" ::: "memory");
    __builtin_amdgcn_sched_barrier(0);
    __builtin_amdgcn_s_setprio(1);
    mm_phase<0, 0>(acc, av, bv);
    __builtin_amdgcn_s_setprio(0);
    __builtin_amdgcn_s_barrier();
    // ---- phase 1: (mq0, nq1); stage (kt+2, B0) (B-region reads done at p0) ----
    if (pf) STAGE(bPan0, d * 65536 + 32768, kOff2);
    __builtin_amdgcn_s_barrier();
    __builtin_amdgcn_s_setprio(1);
    mm_phase<0, 1>(acc, av, bv);
    __builtin_amdgcn_s_setprio(0);
    __builtin_amdgcn_s_barrier();
    // ---- phase 2: (mq1, nq0); read av-mq1; stage (kt+2, B1) ----
    RDA(d, 1);
    if (pf) STAGE(bPan1, d * 65536 + 49152, kOff2);
    __builtin_amdgcn_s_barrier();
    asm volatile("s_waitcnt lgkmcnt(0)" ::: "memory");
    __builtin_amdgcn_sched_barrier(0);
    __builtin_amdgcn_s_setprio(1);
    mm_phase<1, 0>(acc, av, bv);
    __builtin_amdgcn_s_setprio(0);
    __builtin_amdgcn_s_barrier();
    // ---- phase 3: (mq1, nq1); stage (kt+2, A0+A1) (A-region reads done at p2) ----
    if (pf) { STAGE(aPan0, d * 65536, kOff2); STAGE(aPan1, d * 65536 + 16384, kOff2); }
    __builtin_amdgcn_s_barrier();
    __builtin_amdgcn_s_setprio(1);
    mm_phase<1, 1>(acc, av, bv);
    __builtin_amdgcn_s_setprio(0);
    if (pf) { asm volatile("s_waitcnt vmcnt(8)" ::: "memory"); }
    else    { asm volatile("s_waitcnt vmcnt(0)" ::: "memory"); }
    __builtin_amdgcn_sched_barrier(0);
    __builtin_amdgcn_s_barrier();
  }

  // ---- epilogue: y = sinh( 2*zn * asinh( (2*dot*ch - (1+cx2)*sh) / (1-cx2) ) ) ----
  int cr = lane >> 4, cc = lane & 15;
  #pragma unroll
  for (int fn = 0; fn < 4; ++fn) {
    int c = bn0 + wn * 64 + fn * 16 + cc;
    float chc = ch[c], shc = sh[c], z2 = zn2[c];
    #pragma unroll
    for (int fm = 0; fm < 8; ++fm) {
      int rb = bm0 + wm * 128 + fm * 16 + cr * 4;
      #pragma unroll
      for (int j = 0; j < 4; ++j) {
        int r = rb + j;
        float c2 = cx2[r], inv = invomc[r];
        float dot = acc[fm][fn][j];
        float num = 2.f * dot * chc - (1.f + c2) * shc;
        float mlr = z2 * asinhf(num * inv);
        out[(size_t)r * N + c] = sinhf(mlr);
      }
    }
  }
}

// ---------- K3: ball-lift + logmap0, in place on d_out ----------
__global__ void k_final(float* __restrict__ out, int N) {
  int row = blockIdx.x;
  float* yr = out + (size_t)row * N;
  int t = threadIdx.x;
  float v[16];
  float s = 0.f;
  int nit = N >> 8;
  #pragma unroll
  for (int i = 0; i < 16; ++i) {
    if (i < nit) { v[i] = yr[t + (i << 8)]; s += v[i] * v[i]; }
  }
  float ny2 = block_reduce_sum_256(s);
  float ny = sqrtf(ny2);
  float sfac = 1.f / (1.f + sqrtf(1.f + ny2));
  float w = sfac * ny;
  float nw = fmaxf(w, EPSF);
  float tt = fminf(nw, 1.f - EPSF);
  float coef = atanhf(tt) * sfac / nw;
  #pragma unroll
  for (int i = 0; i < 16; ++i) {
    if (i < nit) yr[t + (i << 8)] = coef * v[i];
  }
}

extern "C" void kernel_launch(void* const* d_in, const int* in_sizes, int n_in,
                              void* d_out, int out_size, void* d_ws, size_t ws_size,
                              hipStream_t stream) {
  const float* x    = (const float*)d_in[0];
  const float* z    = (const float*)d_in[1];
  const float* bias = (const float*)d_in[2];
  float* out = (float*)d_out;

  int N = in_sizes[2];           // DOUT = 4096
  int K = in_sizes[1] / N;       // DIN  = 4096
  int M = in_sizes[0] / K;       // B    = 8192

  char* ws = (char*)d_ws;
  size_t o = 0;
  __hip_bfloat16* h  = (__hip_bfloat16*)(ws + o); o += (size_t)M * K * 2;
  __hip_bfloat16* zt = (__hip_bfloat16*)(ws + o); o += (size_t)N * K * 2;
  float* cx2    = (float*)(ws + o); o += (size_t)M * 4;
  float* invomc = (float*)(ws + o); o += (size_t)M * 4;
  float* part   = (float*)(ws + o); o += (size_t)32 * N * 4;
  float* zn2    = (float*)(ws + o); o += (size_t)N * 4;
  float* invzn  = (float*)(ws + o); o += (size_t)N * 4;
  float* chb    = (float*)(ws + o); o += (size_t)N * 4;
  float* shb    = (float*)(ws + o); o += (size_t)N * 4;

  const int NCH = 32;
  k_expmap<<<M, 256, 0, stream>>>(x, h, cx2, invomc, K);
  k_colsq<<<dim3(N / 256, NCH), 256, 0, stream>>>(z, part, K, N, K / NCH);
  k_colfin<<<N / 256, 256, 0, stream>>>(part, bias, zn2, invzn, chb, shb, N, NCH);
  k_zunitT<<<dim3(N / 32, K / 32), dim3(32, 8), 0, stream>>>(z, invzn, zt, K, N);
  int grid = (M / 256) * (N / 256);
  k_gemm_epi<<<grid, 512, 0, stream>>>(h, zt, cx2, invomc, zn2, chb, shb, out, M, N, K);
  k_final<<<M, 256, 0, stream>>>(out, N);
}

// Round 4
// 713.288 us; speedup vs baseline: 1.0086x; 1.0086x over previous
//
#include <hip/hip_runtime.h>
#include <hip/hip_bf16.h>
#include <math.h>

#define EPSF 1e-5f

typedef __attribute__((ext_vector_type(4))) float f32x4;
typedef __attribute__((ext_vector_type(8))) short s16x8;

// ---------- block reduction (256 threads = 4 waves) ----------
__device__ __forceinline__ float block_reduce_sum_256(float s) {
  #pragma unroll
  for (int o = 32; o > 0; o >>= 1) s += __shfl_xor(s, o, 64);
  __shared__ float red[4];
  int lane = threadIdx.x & 63, wid = threadIdx.x >> 6;
  if (lane == 0) red[wid] = s;
  __syncthreads();
  return red[0] + red[1] + red[2] + red[3];
}

// ---------- K0: h = expmap0(x) as bf16; cx2, 1/(1-cx2) per row ----------
__global__ void k_expmap(const float* __restrict__ x, __hip_bfloat16* __restrict__ h,
                         float* __restrict__ cx2, float* __restrict__ invomc, int K) {
  int row = blockIdx.x;
  const float* xr = x + (size_t)row * K;
  int t = threadIdx.x;
  float v[16];
  float s = 0.f;
  int nit = K >> 8;
  #pragma unroll
  for (int i = 0; i < 16; ++i) {
    if (i < nit) { v[i] = xr[t + (i << 8)]; s += v[i] * v[i]; }
  }
  float nsq = block_reduce_sum_256(s);
  float n = fmaxf(sqrtf(nsq), EPSF);
  float sc = tanhf(n) / n;            // rc = 1
  float hn2 = sc * sc * nsq;          // ||h||^2
  float c2 = fminf(hn2, 1.f - EPSF);
  if (t == 0) { cx2[row] = c2; invomc[row] = 1.f / (1.f - c2); }
  __hip_bfloat16* hr = h + (size_t)row * K;
  #pragma unroll
  for (int i = 0; i < 16; ++i) {
    if (i < nit) hr[t + (i << 8)] = __float2bfloat16(sc * v[i]);
  }
}

// ---------- K1a: partial column sum-of-squares of z (deterministic) ----------
__global__ void k_colsq(const float* __restrict__ z, float* __restrict__ part,
                        int K, int N, int rows_per_chunk) {
  int col = blockIdx.x * 256 + threadIdx.x;
  int r0 = blockIdx.y * rows_per_chunk;
  float s = 0.f;
  for (int r = r0; r < r0 + rows_per_chunk; ++r) {
    float v = z[(size_t)r * N + col];
    s += v * v;
  }
  part[(size_t)blockIdx.y * N + col] = s;
}

// ---------- K1b: finalize per-column scalars ----------
__global__ void k_colfin(const float* __restrict__ part, const float* __restrict__ bias,
                         float* __restrict__ zn2, float* __restrict__ invzn,
                         float* __restrict__ ch, float* __restrict__ sh,
                         int N, int nchunk) {
  int c = blockIdx.x * 256 + threadIdx.x;
  float s = 0.f;
  for (int i = 0; i < nchunk; ++i) s += part[(size_t)i * N + c];
  float zn = fmaxf(sqrtf(s), EPSF);
  zn2[c] = 2.f * zn;
  invzn[c] = 1.f / zn;
  float d = 2.f * bias[c];
  ch[c] = coshf(d);
  sh[c] = sinhf(d);
}

// ---------- K1c: z_unit^T (N x K) bf16, LDS tile transpose ----------
__global__ void k_zunitT(const float* __restrict__ z, const float* __restrict__ invzn,
                         __hip_bfloat16* __restrict__ zt, int K, int N) {
  __shared__ float tile[32][33];
  int tx = threadIdx.x, ty = threadIdx.y;   // (32,8)
  int c0 = blockIdx.x * 32, r0 = blockIdx.y * 32;
  float inv = invzn[c0 + tx];
  #pragma unroll
  for (int i = 0; i < 4; ++i)
    tile[ty + i * 8][tx] = z[(size_t)(r0 + ty + i * 8) * N + c0 + tx] * inv;
  __syncthreads();
  #pragma unroll
  for (int i = 0; i < 4; ++i)
    zt[(size_t)(c0 + ty + i * 8) * K + r0 + tx] = __float2bfloat16(tile[tx][ty + i * 8]);
}

// ---------- MFMA phase helper (compile-time quadrant) ----------
template<int MQ, int NQ>
__device__ __forceinline__ void mm_phase(f32x4 (&acc)[8][4], const s16x8 (&av)[4][2],
                                         const s16x8 (&bv)[4][2]) {
  #pragma unroll
  for (int i = 0; i < 4; ++i) {
    #pragma unroll
    for (int jn = 0; jn < 2; ++jn) {
      acc[MQ * 4 + i][NQ * 2 + jn] = __builtin_amdgcn_mfma_f32_16x16x32_bf16(
          av[i][0], bv[NQ * 2 + jn][0], acc[MQ * 4 + i][NQ * 2 + jn], 0, 0, 0);
      acc[MQ * 4 + i][NQ * 2 + jn] = __builtin_amdgcn_mfma_f32_16x16x32_bf16(
          av[i][1], bv[NQ * 2 + jn][1], acc[MQ * 4 + i][NQ * 2 + jn], 0, 0, 0);
    }
  }
}

// force a (uniform) pointer into SGPRs so global_load_lds uses saddr form
__device__ __forceinline__ const char* RFL64(const char* p) {
  unsigned long long b = (unsigned long long)p;
  unsigned int lo = __builtin_amdgcn_readfirstlane((unsigned int)b);
  unsigned int hi = __builtin_amdgcn_readfirstlane((unsigned int)(b >> 32));
  return (const char*)(((unsigned long long)hi << 32) | lo);
}

// ---------- K2: 256x256 8-phase bf16 MFMA GEMM + Poincare-MLR epilogue ----------
// LDS: per dbuf d (64KB): A halves at d*65536 + h*16384, B halves at +32768.
// Half-tile = [128 rows][64 k] bf16, st_16x32 swizzle (byte ^= (row&8)<<2).
// global_load_lds dest is LINEAR; source is inverse-swizzled (rule #21).
// K-loop unrolled x2 so buffer parity D is compile-time (rule #20).
// Phases per K-tile: reads 12/4/8/0, stages 0/0/4(B)/4(A), vmcnt(8) at p3.
__global__ __launch_bounds__(512, 1) void k_gemm_epi(
    const __hip_bfloat16* __restrict__ A,   // h: M x K
    const __hip_bfloat16* __restrict__ Bt,  // z_unit^T: N x K
    const float* __restrict__ cx2, const float* __restrict__ invomc,
    const float* __restrict__ zn2, const float* __restrict__ ch,
    const float* __restrict__ sh,
    float* __restrict__ out, int M, int N, int K) {
  __shared__ __align__(16) char smem[131072];
  const int K2 = K * 2;
  int tid = threadIdx.x, lane = tid & 63, wid = tid >> 6;
  int wm = wid >> 2, wn = wid & 3;

  // bijective XCD swizzle (gridDim.x % 8 == 0 here: 512 blocks)
  int bid = blockIdx.x;
  int cpx = gridDim.x >> 3;
  int swz = (bid & 7) * cpx + (bid >> 3);
  int nbx = N >> 8;
  int bx = swz % nbx, by = swz / nbx;
  int bm0 = by * 256, bn0 = bx * 256;

  // ---- staging: per-lane 32-bit offsets (inverse-swizzled source) ----
  int rr = (tid >> 2) & 15;
  int cbyte = ((tid & 3) * 16) ^ ((rr & 8) << 2);
  int kb = ((tid >> 6) & 1) * 64 + cbyte;          // k-byte within tile [0,128)
  int r0 = ((tid >> 7) << 4) + rr;                 // row (j=0); j=1 adds 64
  unsigned int off0 = (unsigned int)(r0 * K2 + kb);
  unsigned int off1 = off0 + (unsigned int)(64 * K2);
  int ldsW = wid * 1024;                           // linear dest (lane*16 implicit)

  const char* aPan0 = (const char*)A + (size_t)bm0 * K2;
  const char* aPan1 = aPan0 + (size_t)128 * K2;
  const char* bPan0 = (const char*)Bt + (size_t)bn0 * K2;
  const char* bPan1 = bPan0 + (size_t)128 * K2;

  auto STAGE = [&](const char* base, int ldsBase) {
    __builtin_amdgcn_global_load_lds(
        (const __attribute__((address_space(1))) unsigned int*)(base + off0),
        (__attribute__((address_space(3))) unsigned int*)(smem + ldsBase + ldsW), 16, 0, 0);
    __builtin_amdgcn_global_load_lds(
        (const __attribute__((address_space(1))) unsigned int*)(base + off1),
        (__attribute__((address_space(3))) unsigned int*)(smem + ldsBase + ldsW + 8192), 16, 0, 0);
  };

  // ---- LDS read bases (swizzled), one VGPR per buffer per operand ----
  int labase = (lane & 15) * 64 + (((lane >> 4) * 16) ^ ((lane & 8) << 2));
  const char* pA0 = smem + wm * 16384 + labase;
  const char* pA1 = pA0 + 65536;
  const char* pB0 = smem + 32768 + (wn >> 1) * 16384 + (wn & 1) * 8192 + labase;
  const char* pB1 = pB0 + 65536;

  s16x8 av[4][2], bv[4][2];
  f32x4 acc[8][4] = {};

  // all sub-tile offsets are compile-time ds_read offset: immediates (<=15360)
#define RDA(D, MQ) do { const char* p_ = ((D) ? pA1 : pA0); \
    _Pragma("unroll") for (int i_ = 0; i_ < 4; ++i_) { \
      av[i_][0] = *(const s16x8*)(p_ + (MQ) * 8192 + i_ * 2048); \
      av[i_][1] = *(const s16x8*)(p_ + (MQ) * 8192 + i_ * 2048 + 1024); } } while (0)
#define RDB01(D) do { const char* p_ = ((D) ? pB1 : pB0); \
    _Pragma("unroll") for (int f_ = 0; f_ < 2; ++f_) { \
      bv[f_][0] = *(const s16x8*)(p_ + f_ * 2048); \
      bv[f_][1] = *(const s16x8*)(p_ + f_ * 2048 + 1024); } } while (0)
#define RDB23(D) do { const char* p_ = ((D) ? pB1 : pB0); \
    _Pragma("unroll") for (int f_ = 2; f_ < 4; ++f_) { \
      bv[f_][0] = *(const s16x8*)(p_ + f_ * 2048); \
      bv[f_][1] = *(const s16x8*)(p_ + f_ * 2048 + 1024); } } while (0)

  int NT = K >> 6;   // K-tiles of 64 (assumed even)

  // ---- prologue: stage tile0 (8 loads) + tile1 (8 loads) ----
  {
    const char* a0 = RFL64(aPan0); const char* a1 = RFL64(aPan1);
    const char* b0 = RFL64(bPan0); const char* b1 = RFL64(bPan1);
    STAGE(b0, 32768); STAGE(b1, 49152); STAGE(a0, 0); STAGE(a1, 16384);
  }
  if (NT > 1) {
    const char* a0 = RFL64(aPan0 + 128); const char* a1 = RFL64(aPan1 + 128);
    const char* b0 = RFL64(bPan0 + 128); const char* b1 = RFL64(bPan1 + 128);
    STAGE(b0, 65536 + 32768); STAGE(b1, 65536 + 49152);
    STAGE(a0, 65536); STAGE(a1, 65536 + 16384);
    asm volatile("s_waitcnt vmcnt(8)" ::: "memory");
  } else {
    asm volatile("s_waitcnt vmcnt(0)" ::: "memory");
  }
  __builtin_amdgcn_sched_barrier(0);
  __builtin_amdgcn_s_barrier();

#define KTILE(D, KT) do { \
    bool pf_ = ((KT) + 2 < NT); \
    int kOff2_ = ((KT) + 2) << 7; \
    const char* aB0_ = RFL64(aPan0 + kOff2_); \
    const char* aB1_ = RFL64(aPan1 + kOff2_); \
    const char* bB0_ = RFL64(bPan0 + kOff2_); \
    const char* bB1_ = RFL64(bPan1 + kOff2_); \
    /* p0: (0,0) */ \
    RDA(D, 0); RDB01(D); \
    __builtin_amdgcn_s_barrier(); \
    asm volatile("s_waitcnt lgkmcnt(0)" ::: "memory"); \
    __builtin_amdgcn_sched_barrier(0); \
    __builtin_amdgcn_s_setprio(1); mm_phase<0, 0>(acc, av, bv); __builtin_amdgcn_s_setprio(0); \
    __builtin_amdgcn_s_barrier(); \
    /* p1: (0,1) */ \
    RDB23(D); \
    __builtin_amdgcn_s_barrier(); \
    asm volatile("s_waitcnt lgkmcnt(0)" ::: "memory"); \
    __builtin_amdgcn_sched_barrier(0); \
    __builtin_amdgcn_s_setprio(1); mm_phase<0, 1>(acc, av, bv); __builtin_amdgcn_s_setprio(0); \
    __builtin_amdgcn_s_barrier(); \
    /* p2: (1,0); stage B(kt+2) (B-region reads complete) */ \
    RDA(D, 1); \
    if (pf_) { STAGE(bB0_, (D) * 65536 + 32768); STAGE(bB1_, (D) * 65536 + 49152); } \
    __builtin_amdgcn_s_barrier(); \
    asm volatile("s_waitcnt lgkmcnt(0)" ::: "memory"); \
    __builtin_amdgcn_sched_barrier(0); \
    __builtin_amdgcn_s_setprio(1); mm_phase<1, 0>(acc, av, bv); __builtin_amdgcn_s_setprio(0); \
    __builtin_amdgcn_s_barrier(); \
    /* p3: (1,1); stage A(kt+2) (A-region reads complete) */ \
    if (pf_) { STAGE(aB0_, (D) * 65536); STAGE(aB1_, (D) * 65536 + 16384); } \
    __builtin_amdgcn_s_barrier(); \
    __builtin_amdgcn_s_setprio(1); mm_phase<1, 1>(acc, av, bv); __builtin_amdgcn_s_setprio(0); \
    if (pf_) { asm volatile("s_waitcnt vmcnt(8)" ::: "memory"); } \
    else     { asm volatile("s_waitcnt vmcnt(0)" ::: "memory"); } \
    __builtin_amdgcn_sched_barrier(0); \
    __builtin_amdgcn_s_barrier(); \
  } while (0)

  for (int kt = 0; kt < NT; kt += 2) {
    KTILE(0, kt);
    KTILE(1, kt + 1);
  }
#undef KTILE
#undef RDA
#undef RDB01
#undef RDB23

  // ---- epilogue: y = sinh( 2*zn * asinh( (2*dot*ch - (1+cx2)*sh) / (1-cx2) ) ) ----
  int cr = lane >> 4, cc = lane & 15;
  #pragma unroll
  for (int fn = 0; fn < 4; ++fn) {
    int c = bn0 + wn * 64 + fn * 16 + cc;
    float chc = ch[c], shc = sh[c], z2 = zn2[c];
    #pragma unroll
    for (int fm = 0; fm < 8; ++fm) {
      int rb = bm0 + wm * 128 + fm * 16 + cr * 4;
      #pragma unroll
      for (int j = 0; j < 4; ++j) {
        int r = rb + j;
        float c2 = cx2[r], inv = invomc[r];
        float dot = acc[fm][fn][j];
        float num = 2.f * dot * chc - (1.f + c2) * shc;
        float mlr = z2 * asinhf(num * inv);
        out[(size_t)r * N + c] = sinhf(mlr);
      }
    }
  }
}

// ---------- K3: ball-lift + logmap0, in place on d_out ----------
__global__ void k_final(float* __restrict__ out, int N) {
  int row = blockIdx.x;
  float* yr = out + (size_t)row * N;
  int t = threadIdx.x;
  float v[16];
  float s = 0.f;
  int nit = N >> 8;
  #pragma unroll
  for (int i = 0; i < 16; ++i) {
    if (i < nit) { v[i] = yr[t + (i << 8)]; s += v[i] * v[i]; }
  }
  float ny2 = block_reduce_sum_256(s);
  float ny = sqrtf(ny2);
  float sfac = 1.f / (1.f + sqrtf(1.f + ny2));
  float w = sfac * ny;
  float nw = fmaxf(w, EPSF);
  float tt = fminf(nw, 1.f - EPSF);
  float coef = atanhf(tt) * sfac / nw;
  #pragma unroll
  for (int i = 0; i < 16; ++i) {
    if (i < nit) yr[t + (i << 8)] = coef * v[i];
  }
}

extern "C" void kernel_launch(void* const* d_in, const int* in_sizes, int n_in,
                              void* d_out, int out_size, void* d_ws, size_t ws_size,
                              hipStream_t stream) {
  const float* x    = (const float*)d_in[0];
  const float* z    = (const float*)d_in[1];
  const float* bias = (const float*)d_in[2];
  float* out = (float*)d_out;

  int N = in_sizes[2];           // DOUT = 4096
  int K = in_sizes[1] / N;       // DIN  = 4096
  int M = in_sizes[0] / K;       // B    = 8192

  char* ws = (char*)d_ws;
  size_t o = 0;
  __hip_bfloat16* h  = (__hip_bfloat16*)(ws + o); o += (size_t)M * K * 2;
  __hip_bfloat16* zt = (__hip_bfloat16*)(ws + o); o += (size_t)N * K * 2;
  float* cx2    = (float*)(ws + o); o += (size_t)M * 4;
  float* invomc = (float*)(ws + o); o += (size_t)M * 4;
  float* part   = (float*)(ws + o); o += (size_t)32 * N * 4;
  float* zn2    = (float*)(ws + o); o += (size_t)N * 4;
  float* invzn  = (float*)(ws + o); o += (size_t)N * 4;
  float* chb    = (float*)(ws + o); o += (size_t)N * 4;
  float* shb    = (float*)(ws + o); o += (size_t)N * 4;

  const int NCH = 32;
  k_expmap<<<M, 256, 0, stream>>>(x, h, cx2, invomc, K);
  k_colsq<<<dim3(N / 256, NCH), 256, 0, stream>>>(z, part, K, N, K / NCH);
  k_colfin<<<N / 256, 256, 0, stream>>>(part, bias, zn2, invzn, chb, shb, N, NCH);
  k_zunitT<<<dim3(N / 32, K / 32), dim3(32, 8), 0, stream>>>(z, invzn, zt, K, N);
  int grid = (M / 256) * (N / 256);
  k_gemm_epi<<<grid, 512, 0, stream>>>(h, zt, cx2, invomc, zn2, chb, shb, out, M, N, K);
  k_final<<<M, 256, 0, stream>>>(out, N);
}

// Round 5
// 713.026 us; speedup vs baseline: 1.0090x; 1.0004x over previous
//
#include <hip/hip_runtime.h>
#include <hip/hip_bf16.h>
#include <math.h>

#define EPSF 1e-5f

typedef __attribute__((ext_vector_type(4))) float f32x4;
typedef __attribute__((ext_vector_type(8))) short s16x8;

// ---------- block reduction (256 threads = 4 waves) ----------
__device__ __forceinline__ float block_reduce_sum_256(float s) {
  #pragma unroll
  for (int o = 32; o > 0; o >>= 1) s += __shfl_xor(s, o, 64);
  __shared__ float red[4];
  int lane = threadIdx.x & 63, wid = threadIdx.x >> 6;
  if (lane == 0) red[wid] = s;
  __syncthreads();
  return red[0] + red[1] + red[2] + red[3];
}

// ---------- K0: h = expmap0(x) as bf16; cx2, 1/(1-cx2) per row ----------
__global__ void k_expmap(const float* __restrict__ x, __hip_bfloat16* __restrict__ h,
                         float* __restrict__ cx2, float* __restrict__ invomc, int K) {
  int row = blockIdx.x;
  const float* xr = x + (size_t)row * K;
  int t = threadIdx.x;
  float v[16];
  float s = 0.f;
  int nit = K >> 8;
  #pragma unroll
  for (int i = 0; i < 16; ++i) {
    if (i < nit) { v[i] = xr[t + (i << 8)]; s += v[i] * v[i]; }
  }
  float nsq = block_reduce_sum_256(s);
  float n = fmaxf(sqrtf(nsq), EPSF);
  float sc = tanhf(n) / n;            // rc = 1
  float hn2 = sc * sc * nsq;          // ||h||^2
  float c2 = fminf(hn2, 1.f - EPSF);
  if (t == 0) { cx2[row] = c2; invomc[row] = 1.f / (1.f - c2); }
  __hip_bfloat16* hr = h + (size_t)row * K;
  #pragma unroll
  for (int i = 0; i < 16; ++i) {
    if (i < nit) hr[t + (i << 8)] = __float2bfloat16(sc * v[i]);
  }
}

// ---------- K1a: partial column sum-of-squares of z (deterministic) ----------
__global__ void k_colsq(const float* __restrict__ z, float* __restrict__ part,
                        int K, int N, int rows_per_chunk) {
  int col = blockIdx.x * 256 + threadIdx.x;
  int r0 = blockIdx.y * rows_per_chunk;
  float s = 0.f;
  for (int r = r0; r < r0 + rows_per_chunk; ++r) {
    float v = z[(size_t)r * N + col];
    s += v * v;
  }
  part[(size_t)blockIdx.y * N + col] = s;
}

// ---------- K1b: finalize per-column scalars ----------
__global__ void k_colfin(const float* __restrict__ part, const float* __restrict__ bias,
                         float* __restrict__ zn2, float* __restrict__ invzn,
                         float* __restrict__ ch, float* __restrict__ sh,
                         int N, int nchunk) {
  int c = blockIdx.x * 256 + threadIdx.x;
  float s = 0.f;
  for (int i = 0; i < nchunk; ++i) s += part[(size_t)i * N + c];
  float zn = fmaxf(sqrtf(s), EPSF);
  zn2[c] = 2.f * zn;
  invzn[c] = 1.f / zn;
  float d = 2.f * bias[c];
  ch[c] = coshf(d);
  sh[c] = sinhf(d);
}

// ---------- K1c: z_unit^T (N x K) bf16, LDS tile transpose ----------
__global__ void k_zunitT(const float* __restrict__ z, const float* __restrict__ invzn,
                         __hip_bfloat16* __restrict__ zt, int K, int N) {
  __shared__ float tile[32][33];
  int tx = threadIdx.x, ty = threadIdx.y;   // (32,8)
  int c0 = blockIdx.x * 32, r0 = blockIdx.y * 32;
  float inv = invzn[c0 + tx];
  #pragma unroll
  for (int i = 0; i < 4; ++i)
    tile[ty + i * 8][tx] = z[(size_t)(r0 + ty + i * 8) * N + c0 + tx] * inv;
  __syncthreads();
  #pragma unroll
  for (int i = 0; i < 4; ++i)
    zt[(size_t)(c0 + ty + i * 8) * K + r0 + tx] = __float2bfloat16(tile[tx][ty + i * 8]);
}

// ---------- MFMA phase helper (compile-time quadrant) ----------
template<int MQ, int NQ>
__device__ __forceinline__ void mm_phase(f32x4 (&acc)[8][4], const s16x8 (&av)[4][2],
                                         const s16x8 (&bv)[4][2]) {
  #pragma unroll
  for (int i = 0; i < 4; ++i) {
    #pragma unroll
    for (int jn = 0; jn < 2; ++jn) {
      acc[MQ * 4 + i][NQ * 2 + jn] = __builtin_amdgcn_mfma_f32_16x16x32_bf16(
          av[i][0], bv[NQ * 2 + jn][0], acc[MQ * 4 + i][NQ * 2 + jn], 0, 0, 0);
      acc[MQ * 4 + i][NQ * 2 + jn] = __builtin_amdgcn_mfma_f32_16x16x32_bf16(
          av[i][1], bv[NQ * 2 + jn][1], acc[MQ * 4 + i][NQ * 2 + jn], 0, 0, 0);
    }
  }
}

// force a (uniform) pointer into SGPRs so global_load_lds uses saddr form
__device__ __forceinline__ const char* RFL64(const char* p) {
  unsigned long long b = (unsigned long long)p;
  unsigned int lo = __builtin_amdgcn_readfirstlane((unsigned int)b);
  unsigned int hi = __builtin_amdgcn_readfirstlane((unsigned int)(b >> 32));
  return (const char*)(((unsigned long long)hi << 32) | lo);
}

// ---------- K2: 256x256 8-phase bf16 MFMA GEMM + Poincare-MLR epilogue ----------
// LDS: per dbuf d (64KB): A halves at d*65536 + h*16384, B halves at +32768.
// Half-tile = [128 rows][64 k] bf16, st_16x32 swizzle (byte ^= (row&8)<<2).
// global_load_lds dest is LINEAR; source is inverse-swizzled (rule #21).
// K-loop unrolled x2 so buffer parity D is compile-time (rule #20).
// Phases per K-tile: reads 12/4/8/0, stages 0/0/4(B)/4(A), vmcnt(8) at p3.
// NOTE: waitcnt asms are BARE (no "memory" clobber) per the verified m201
// template — a memory clobber forces the waitcnt pass to conservatively
// drain vmcnt(0) around the asm, collapsing the counted-vmcnt pipeline.
// WAR safety holds structurally: every phase's ds_reads feed that phase's
// MFMAs (compiler inserts precise lgkmcnt), and the phase-end barrier
// orders them against the next phase's STAGE.
__global__ __launch_bounds__(512, 1) void k_gemm_epi(
    const __hip_bfloat16* __restrict__ A,   // h: M x K
    const __hip_bfloat16* __restrict__ Bt,  // z_unit^T: N x K
    const float* __restrict__ cx2, const float* __restrict__ invomc,
    const float* __restrict__ zn2, const float* __restrict__ ch,
    const float* __restrict__ sh,
    float* __restrict__ out, int M, int N, int K) {
  __shared__ __align__(16) char smem[131072];
  const int K2 = K * 2;
  int tid = threadIdx.x, lane = tid & 63, wid = tid >> 6;
  int wm = wid >> 2, wn = wid & 3;

  // bijective XCD swizzle (gridDim.x % 8 == 0 here: 512 blocks)
  int bid = blockIdx.x;
  int cpx = gridDim.x >> 3;
  int swz = (bid & 7) * cpx + (bid >> 3);
  int nbx = N >> 8;
  int bx = swz % nbx, by = swz / nbx;
  int bm0 = by * 256, bn0 = bx * 256;

  // ---- staging: per-lane 32-bit offsets (inverse-swizzled source) ----
  int rr = (tid >> 2) & 15;
  int cbyte = ((tid & 3) * 16) ^ ((rr & 8) << 2);
  int kb = ((tid >> 6) & 1) * 64 + cbyte;          // k-byte within tile [0,128)
  int r0 = ((tid >> 7) << 4) + rr;                 // row (j=0); j=1 adds 64
  unsigned int off0 = (unsigned int)(r0 * K2 + kb);
  unsigned int off1 = off0 + (unsigned int)(64 * K2);
  int ldsW = wid * 1024;                           // linear dest (lane*16 implicit)

  const char* aPan0 = (const char*)A + (size_t)bm0 * K2;
  const char* aPan1 = aPan0 + (size_t)128 * K2;
  const char* bPan0 = (const char*)Bt + (size_t)bn0 * K2;
  const char* bPan1 = bPan0 + (size_t)128 * K2;

  auto STAGE = [&](const char* base, int ldsBase) {
    __builtin_amdgcn_global_load_lds(
        (const __attribute__((address_space(1))) unsigned int*)(base + off0),
        (__attribute__((address_space(3))) unsigned int*)(smem + ldsBase + ldsW), 16, 0, 0);
    __builtin_amdgcn_global_load_lds(
        (const __attribute__((address_space(1))) unsigned int*)(base + off1),
        (__attribute__((address_space(3))) unsigned int*)(smem + ldsBase + ldsW + 8192), 16, 0, 0);
  };

  // ---- LDS read bases (swizzled), one VGPR per buffer per operand ----
  int labase = (lane & 15) * 64 + (((lane >> 4) * 16) ^ ((lane & 8) << 2));
  const char* pA0 = smem + wm * 16384 + labase;
  const char* pA1 = pA0 + 65536;
  const char* pB0 = smem + 32768 + (wn >> 1) * 16384 + (wn & 1) * 8192 + labase;
  const char* pB1 = pB0 + 65536;

  s16x8 av[4][2], bv[4][2];
  f32x4 acc[8][4] = {};

  // all sub-tile offsets are compile-time ds_read offset: immediates
#define RDA(D, MQ) do { const char* p_ = ((D) ? pA1 : pA0); \
    _Pragma("unroll") for (int i_ = 0; i_ < 4; ++i_) { \
      av[i_][0] = *(const s16x8*)(p_ + (MQ) * 8192 + i_ * 2048); \
      av[i_][1] = *(const s16x8*)(p_ + (MQ) * 8192 + i_ * 2048 + 1024); } } while (0)
#define RDB01(D) do { const char* p_ = ((D) ? pB1 : pB0); \
    _Pragma("unroll") for (int f_ = 0; f_ < 2; ++f_) { \
      bv[f_][0] = *(const s16x8*)(p_ + f_ * 2048); \
      bv[f_][1] = *(const s16x8*)(p_ + f_ * 2048 + 1024); } } while (0)
#define RDB23(D) do { const char* p_ = ((D) ? pB1 : pB0); \
    _Pragma("unroll") for (int f_ = 2; f_ < 4; ++f_) { \
      bv[f_][0] = *(const s16x8*)(p_ + f_ * 2048); \
      bv[f_][1] = *(const s16x8*)(p_ + f_ * 2048 + 1024); } } while (0)

  int NT = K >> 6;   // K-tiles of 64 (assumed even)

  // ---- prologue: stage tile0 (8 loads) + tile1 (8 loads) ----
  {
    const char* a0 = RFL64(aPan0); const char* a1 = RFL64(aPan1);
    const char* b0 = RFL64(bPan0); const char* b1 = RFL64(bPan1);
    STAGE(b0, 32768); STAGE(b1, 49152); STAGE(a0, 0); STAGE(a1, 16384);
  }
  if (NT > 1) {
    const char* a0 = RFL64(aPan0 + 128); const char* a1 = RFL64(aPan1 + 128);
    const char* b0 = RFL64(bPan0 + 128); const char* b1 = RFL64(bPan1 + 128);
    STAGE(b0, 65536 + 32768); STAGE(b1, 65536 + 49152);
    STAGE(a0, 65536); STAGE(a1, 65536 + 16384);
    asm volatile("s_waitcnt vmcnt(8)");
  } else {
    asm volatile("s_waitcnt vmcnt(0)");
  }
  __builtin_amdgcn_s_barrier();

#define KTILE(D, KT) do { \
    bool pf_ = ((KT) + 2 < NT); \
    int kOff2_ = ((KT) + 2) << 7; \
    const char* aB0_ = RFL64(aPan0 + kOff2_); \
    const char* aB1_ = RFL64(aPan1 + kOff2_); \
    const char* bB0_ = RFL64(bPan0 + kOff2_); \
    const char* bB1_ = RFL64(bPan1 + kOff2_); \
    /* p0: (0,0) */ \
    RDA(D, 0); RDB01(D); \
    __builtin_amdgcn_s_barrier(); \
    asm volatile("s_waitcnt lgkmcnt(0)"); \
    __builtin_amdgcn_s_setprio(1); mm_phase<0, 0>(acc, av, bv); __builtin_amdgcn_s_setprio(0); \
    __builtin_amdgcn_s_barrier(); \
    /* p1: (0,1) */ \
    RDB23(D); \
    __builtin_amdgcn_s_barrier(); \
    asm volatile("s_waitcnt lgkmcnt(0)"); \
    __builtin_amdgcn_s_setprio(1); mm_phase<0, 1>(acc, av, bv); __builtin_amdgcn_s_setprio(0); \
    __builtin_amdgcn_s_barrier(); \
    /* p2: (1,0); stage B(kt+2) (B-region reads complete) */ \
    RDA(D, 1); \
    if (pf_) { STAGE(bB0_, (D) * 65536 + 32768); STAGE(bB1_, (D) * 65536 + 49152); } \
    __builtin_amdgcn_s_barrier(); \
    asm volatile("s_waitcnt lgkmcnt(0)"); \
    __builtin_amdgcn_s_setprio(1); mm_phase<1, 0>(acc, av, bv); __builtin_amdgcn_s_setprio(0); \
    __builtin_amdgcn_s_barrier(); \
    /* p3: (1,1); stage A(kt+2) (A-region reads complete) */ \
    if (pf_) { STAGE(aB0_, (D) * 65536); STAGE(aB1_, (D) * 65536 + 16384); } \
    __builtin_amdgcn_s_barrier(); \
    __builtin_amdgcn_s_setprio(1); mm_phase<1, 1>(acc, av, bv); __builtin_amdgcn_s_setprio(0); \
    if (pf_) { asm volatile("s_waitcnt vmcnt(8)"); } \
    else     { asm volatile("s_waitcnt vmcnt(0)"); } \
    __builtin_amdgcn_s_barrier(); \
  } while (0)

  for (int kt = 0; kt < NT; kt += 2) {
    KTILE(0, kt);
    KTILE(1, kt + 1);
  }
#undef KTILE
#undef RDA
#undef RDB01
#undef RDB23

  // ---- epilogue: y = sinh( 2*zn * asinh( (2*dot*ch - (1+cx2)*sh) / (1-cx2) ) ) ----
  int cr = lane >> 4, cc = lane & 15;
  #pragma unroll
  for (int fn = 0; fn < 4; ++fn) {
    int c = bn0 + wn * 64 + fn * 16 + cc;
    float chc = ch[c], shc = sh[c], z2 = zn2[c];
    #pragma unroll
    for (int fm = 0; fm < 8; ++fm) {
      int rb = bm0 + wm * 128 + fm * 16 + cr * 4;
      #pragma unroll
      for (int j = 0; j < 4; ++j) {
        int r = rb + j;
        float c2 = cx2[r], inv = invomc[r];
        float dot = acc[fm][fn][j];
        float num = 2.f * dot * chc - (1.f + c2) * shc;
        float mlr = z2 * asinhf(num * inv);
        out[(size_t)r * N + c] = sinhf(mlr);
      }
    }
  }
}

// ---------- K3: ball-lift + logmap0, in place on d_out ----------
__global__ void k_final(float* __restrict__ out, int N) {
  int row = blockIdx.x;
  float* yr = out + (size_t)row * N;
  int t = threadIdx.x;
  float v[16];
  float s = 0.f;
  int nit = N >> 8;
  #pragma unroll
  for (int i = 0; i < 16; ++i) {
    if (i < nit) { v[i] = yr[t + (i << 8)]; s += v[i] * v[i]; }
  }
  float ny2 = block_reduce_sum_256(s);
  float ny = sqrtf(ny2);
  float sfac = 1.f / (1.f + sqrtf(1.f + ny2));
  float w = sfac * ny;
  float nw = fmaxf(w, EPSF);
  float tt = fminf(nw, 1.f - EPSF);
  float coef = atanhf(tt) * sfac / nw;
  #pragma unroll
  for (int i = 0; i < 16; ++i) {
    if (i < nit) yr[t + (i << 8)] = coef * v[i];
  }
}

extern "C" void kernel_launch(void* const* d_in, const int* in_sizes, int n_in,
                              void* d_out, int out_size, void* d_ws, size_t ws_size,
                              hipStream_t stream) {
  const float* x    = (const float*)d_in[0];
  const float* z    = (const float*)d_in[1];
  const float* bias = (const float*)d_in[2];
  float* out = (float*)d_out;

  int N = in_sizes[2];           // DOUT = 4096
  int K = in_sizes[1] / N;       // DIN  = 4096
  int M = in_sizes[0] / K;       // B    = 8192

  char* ws = (char*)d_ws;
  size_t o = 0;
  __hip_bfloat16* h  = (__hip_bfloat16*)(ws + o); o += (size_t)M * K * 2;
  __hip_bfloat16* zt = (__hip_bfloat16*)(ws + o); o += (size_t)N * K * 2;
  float* cx2    = (float*)(ws + o); o += (size_t)M * 4;
  float* invomc = (float*)(ws + o); o += (size_t)M * 4;
  float* part   = (float*)(ws + o); o += (size_t)32 * N * 4;
  float* zn2    = (float*)(ws + o); o += (size_t)N * 4;
  float* invzn  = (float*)(ws + o); o += (size_t)N * 4;
  float* chb    = (float*)(ws + o); o += (size_t)N * 4;
  float* shb    = (float*)(ws + o); o += (size_t)N * 4;

  const int NCH = 32;
  k_expmap<<<M, 256, 0, stream>>>(x, h, cx2, invomc, K);
  k_colsq<<<dim3(N / 256, NCH), 256, 0, stream>>>(z, part, K, N, K / NCH);
  k_colfin<<<N / 256, 256, 0, stream>>>(part, bias, zn2, invzn, chb, shb, N, NCH);
  k_zunitT<<<dim3(N / 32, K / 32), dim3(32, 8), 0, stream>>>(z, invzn, zt, K, N);
  int grid = (M / 256) * (N / 256);
  k_gemm_epi<<<grid, 512, 0, stream>>>(h, zt, cx2, invomc, zn2, chb, shb, out, M, N, K);
  k_final<<<M, 256, 0, stream>>>(out, N);
}

// Round 6
// 579.244 us; speedup vs baseline: 1.2420x; 1.2310x over previous
//
#include <hip/hip_runtime.h>
#include <hip/hip_bf16.h>
#include <math.h>

#define EPSF 1e-5f

typedef __attribute__((ext_vector_type(4))) float f32x4;
typedef __attribute__((ext_vector_type(8))) short s16x8;

// ---------- block reduction (256 threads = 4 waves) ----------
__device__ __forceinline__ float block_reduce_sum_256(float s) {
  #pragma unroll
  for (int o = 32; o > 0; o >>= 1) s += __shfl_xor(s, o, 64);
  __shared__ float red[4];
  int lane = threadIdx.x & 63, wid = threadIdx.x >> 6;
  if (lane == 0) red[wid] = s;
  __syncthreads();
  return red[0] + red[1] + red[2] + red[3];
}

__device__ __forceinline__ unsigned short f2bu(float f) {
  __hip_bfloat16 b = __float2bfloat16(f);
  return __builtin_bit_cast(unsigned short, b);
}

// ---------- K0: h = expmap0(x) as bf16; cx2, 1/(1-cx2) per row (float4) ----------
__global__ void k_expmap(const float* __restrict__ x, __hip_bfloat16* __restrict__ h,
                         float* __restrict__ cx2, float* __restrict__ invomc, int K) {
  int row = blockIdx.x, t = threadIdx.x;
  const float4* xr = (const float4*)(x + (size_t)row * K);
  float4 v[4];
  float s = 0.f;
  #pragma unroll
  for (int i = 0; i < 4; ++i) {
    v[i] = xr[t + (i << 8)];
    s += v[i].x * v[i].x + v[i].y * v[i].y + v[i].z * v[i].z + v[i].w * v[i].w;
  }
  float nsq = block_reduce_sum_256(s);
  float n = fmaxf(sqrtf(nsq), EPSF);
  float sc = tanhf(n) / n;            // rc = 1
  float hn2 = sc * sc * nsq;          // ||h||^2
  float c2 = fminf(hn2, 1.f - EPSF);
  if (t == 0) { cx2[row] = c2; invomc[row] = 1.f / (1.f - c2); }
  ushort4* hr = (ushort4*)(h + (size_t)row * K);
  #pragma unroll
  for (int i = 0; i < 4; ++i) {
    ushort4 o;
    o.x = f2bu(sc * v[i].x); o.y = f2bu(sc * v[i].y);
    o.z = f2bu(sc * v[i].z); o.w = f2bu(sc * v[i].w);
    hr[t + (i << 8)] = o;
  }
}

// ---------- K1a: partial column sum-of-squares of z (float4, deterministic) ----------
__global__ void k_colsq(const float* __restrict__ z, float* __restrict__ part,
                        int K, int N, int rows_per_chunk) {
  int c4 = blockIdx.x * 256 + threadIdx.x;    // float4 column index
  int r0 = blockIdx.y * rows_per_chunk;
  const float4* z4 = (const float4*)z;
  int n4 = N >> 2;
  float4 a = {0.f, 0.f, 0.f, 0.f};
  for (int r = r0; r < r0 + rows_per_chunk; ++r) {
    float4 v = z4[(size_t)r * n4 + c4];
    a.x += v.x * v.x; a.y += v.y * v.y; a.z += v.z * v.z; a.w += v.w * v.w;
  }
  ((float4*)part)[(size_t)blockIdx.y * n4 + c4] = a;
}

// ---------- K1b: finalize per-column scalars ----------
__global__ void k_colfin(const float* __restrict__ part, const float* __restrict__ bias,
                         float* __restrict__ zn2, float* __restrict__ invzn,
                         float* __restrict__ ch, float* __restrict__ sh,
                         int N, int nchunk) {
  int c = blockIdx.x * 256 + threadIdx.x;
  float s = 0.f;
  for (int i = 0; i < nchunk; ++i) s += part[(size_t)i * N + c];
  float zn = fmaxf(sqrtf(s), EPSF);
  zn2[c] = 2.f * zn;
  invzn[c] = 1.f / zn;
  float d = 2.f * bias[c];
  ch[c] = coshf(d);
  sh[c] = sinhf(d);
}

// ---------- K1c: z_unit^T (N x K) bf16, LDS tile transpose ----------
__global__ void k_zunitT(const float* __restrict__ z, const float* __restrict__ invzn,
                         __hip_bfloat16* __restrict__ zt, int K, int N) {
  __shared__ float tile[32][33];
  int tx = threadIdx.x, ty = threadIdx.y;   // (32,8)
  int c0 = blockIdx.x * 32, r0 = blockIdx.y * 32;
  float inv = invzn[c0 + tx];
  #pragma unroll
  for (int i = 0; i < 4; ++i)
    tile[ty + i * 8][tx] = z[(size_t)(r0 + ty + i * 8) * N + c0 + tx] * inv;
  __syncthreads();
  #pragma unroll
  for (int i = 0; i < 4; ++i)
    zt[(size_t)(c0 + ty + i * 8) * K + r0 + tx] = __float2bfloat16(tile[tx][ty + i * 8]);
}

// ---------- MFMA phase helper (compile-time quadrant) ----------
template<int MQ, int NQ>
__device__ __forceinline__ void mm_phase(f32x4 (&acc)[8][4], const s16x8 (&av)[4][2],
                                         const s16x8 (&bv)[4][2]) {
  #pragma unroll
  for (int i = 0; i < 4; ++i) {
    #pragma unroll
    for (int jn = 0; jn < 2; ++jn) {
      acc[MQ * 4 + i][NQ * 2 + jn] = __builtin_amdgcn_mfma_f32_16x16x32_bf16(
          av[i][0], bv[NQ * 2 + jn][0], acc[MQ * 4 + i][NQ * 2 + jn], 0, 0, 0);
      acc[MQ * 4 + i][NQ * 2 + jn] = __builtin_amdgcn_mfma_f32_16x16x32_bf16(
          av[i][1], bv[NQ * 2 + jn][1], acc[MQ * 4 + i][NQ * 2 + jn], 0, 0, 0);
    }
  }
}

// force a (uniform) pointer into SGPRs so global_load_lds uses saddr form
__device__ __forceinline__ const char* RFL64(const char* p) {
  unsigned long long b = (unsigned long long)p;
  unsigned int lo = __builtin_amdgcn_readfirstlane((unsigned int)b);
  unsigned int hi = __builtin_amdgcn_readfirstlane((unsigned int)(b >> 32));
  return (const char*)(((unsigned long long)hi << 32) | lo);
}

// ---------- K2: 256x256 8-phase bf16 MFMA GEMM -> raw dot products ----------
// Loop identical to R5. Epilogue: raw f32 dot stores, fn-INNERMOST so each
// row's four 64B segments are temporally adjacent (full-line L2 combining).
__global__ __launch_bounds__(512, 1) void k_gemm_dot(
    const __hip_bfloat16* __restrict__ A,   // h: M x K
    const __hip_bfloat16* __restrict__ Bt,  // z_unit^T: N x K
    float* __restrict__ dot, int M, int N, int K) {
  __shared__ __align__(16) char smem[131072];
  const int K2 = K * 2;
  int tid = threadIdx.x, lane = tid & 63, wid = tid >> 6;
  int wm = wid >> 2, wn = wid & 3;

  // bijective XCD swizzle (gridDim.x % 8 == 0 here: 512 blocks)
  int bid = blockIdx.x;
  int cpx = gridDim.x >> 3;
  int swz = (bid & 7) * cpx + (bid >> 3);
  int nbx = N >> 8;
  int bx = swz % nbx, by = swz / nbx;
  int bm0 = by * 256, bn0 = bx * 256;

  // ---- staging: per-lane 32-bit offsets (inverse-swizzled source) ----
  int rr = (tid >> 2) & 15;
  int cbyte = ((tid & 3) * 16) ^ ((rr & 8) << 2);
  int kb = ((tid >> 6) & 1) * 64 + cbyte;          // k-byte within tile [0,128)
  int r0 = ((tid >> 7) << 4) + rr;                 // row (j=0); j=1 adds 64
  unsigned int off0 = (unsigned int)(r0 * K2 + kb);
  unsigned int off1 = off0 + (unsigned int)(64 * K2);
  int ldsW = wid * 1024;                           // linear dest (lane*16 implicit)

  const char* aPan0 = (const char*)A + (size_t)bm0 * K2;
  const char* aPan1 = aPan0 + (size_t)128 * K2;
  const char* bPan0 = (const char*)Bt + (size_t)bn0 * K2;
  const char* bPan1 = bPan0 + (size_t)128 * K2;

  auto STAGE = [&](const char* base, int ldsBase) {
    __builtin_amdgcn_global_load_lds(
        (const __attribute__((address_space(1))) unsigned int*)(base + off0),
        (__attribute__((address_space(3))) unsigned int*)(smem + ldsBase + ldsW), 16, 0, 0);
    __builtin_amdgcn_global_load_lds(
        (const __attribute__((address_space(1))) unsigned int*)(base + off1),
        (__attribute__((address_space(3))) unsigned int*)(smem + ldsBase + ldsW + 8192), 16, 0, 0);
  };

  // ---- LDS read bases (swizzled) ----
  int labase = (lane & 15) * 64 + (((lane >> 4) * 16) ^ ((lane & 8) << 2));
  const char* pA0 = smem + wm * 16384 + labase;
  const char* pA1 = pA0 + 65536;
  const char* pB0 = smem + 32768 + (wn >> 1) * 16384 + (wn & 1) * 8192 + labase;
  const char* pB1 = pB0 + 65536;

  s16x8 av[4][2], bv[4][2];
  f32x4 acc[8][4] = {};

#define RDA(D, MQ) do { const char* p_ = ((D) ? pA1 : pA0); \
    _Pragma("unroll") for (int i_ = 0; i_ < 4; ++i_) { \
      av[i_][0] = *(const s16x8*)(p_ + (MQ) * 8192 + i_ * 2048); \
      av[i_][1] = *(const s16x8*)(p_ + (MQ) * 8192 + i_ * 2048 + 1024); } } while (0)
#define RDB01(D) do { const char* p_ = ((D) ? pB1 : pB0); \
    _Pragma("unroll") for (int f_ = 0; f_ < 2; ++f_) { \
      bv[f_][0] = *(const s16x8*)(p_ + f_ * 2048); \
      bv[f_][1] = *(const s16x8*)(p_ + f_ * 2048 + 1024); } } while (0)
#define RDB23(D) do { const char* p_ = ((D) ? pB1 : pB0); \
    _Pragma("unroll") for (int f_ = 2; f_ < 4; ++f_) { \
      bv[f_][0] = *(const s16x8*)(p_ + f_ * 2048); \
      bv[f_][1] = *(const s16x8*)(p_ + f_ * 2048 + 1024); } } while (0)

  int NT = K >> 6;   // K-tiles of 64 (assumed even)

  // ---- prologue: stage tile0 (8 loads) + tile1 (8 loads) ----
  {
    const char* a0 = RFL64(aPan0); const char* a1 = RFL64(aPan1);
    const char* b0 = RFL64(bPan0); const char* b1 = RFL64(bPan1);
    STAGE(b0, 32768); STAGE(b1, 49152); STAGE(a0, 0); STAGE(a1, 16384);
  }
  if (NT > 1) {
    const char* a0 = RFL64(aPan0 + 128); const char* a1 = RFL64(aPan1 + 128);
    const char* b0 = RFL64(bPan0 + 128); const char* b1 = RFL64(bPan1 + 128);
    STAGE(b0, 65536 + 32768); STAGE(b1, 65536 + 49152);
    STAGE(a0, 65536); STAGE(a1, 65536 + 16384);
    asm volatile("s_waitcnt vmcnt(8)");
  } else {
    asm volatile("s_waitcnt vmcnt(0)");
  }
  __builtin_amdgcn_s_barrier();

#define KTILE(D, KT) do { \
    bool pf_ = ((KT) + 2 < NT); \
    int kOff2_ = ((KT) + 2) << 7; \
    const char* aB0_ = RFL64(aPan0 + kOff2_); \
    const char* aB1_ = RFL64(aPan1 + kOff2_); \
    const char* bB0_ = RFL64(bPan0 + kOff2_); \
    const char* bB1_ = RFL64(bPan1 + kOff2_); \
    /* p0: (0,0) */ \
    RDA(D, 0); RDB01(D); \
    __builtin_amdgcn_s_barrier(); \
    asm volatile("s_waitcnt lgkmcnt(0)"); \
    __builtin_amdgcn_s_setprio(1); mm_phase<0, 0>(acc, av, bv); __builtin_amdgcn_s_setprio(0); \
    __builtin_amdgcn_s_barrier(); \
    /* p1: (0,1) */ \
    RDB23(D); \
    __builtin_amdgcn_s_barrier(); \
    asm volatile("s_waitcnt lgkmcnt(0)"); \
    __builtin_amdgcn_s_setprio(1); mm_phase<0, 1>(acc, av, bv); __builtin_amdgcn_s_setprio(0); \
    __builtin_amdgcn_s_barrier(); \
    /* p2: (1,0); stage B(kt+2) */ \
    RDA(D, 1); \
    if (pf_) { STAGE(bB0_, (D) * 65536 + 32768); STAGE(bB1_, (D) * 65536 + 49152); } \
    __builtin_amdgcn_s_barrier(); \
    asm volatile("s_waitcnt lgkmcnt(0)"); \
    __builtin_amdgcn_s_setprio(1); mm_phase<1, 0>(acc, av, bv); __builtin_amdgcn_s_setprio(0); \
    __builtin_amdgcn_s_barrier(); \
    /* p3: (1,1); stage A(kt+2) */ \
    if (pf_) { STAGE(aB0_, (D) * 65536); STAGE(aB1_, (D) * 65536 + 16384); } \
    __builtin_amdgcn_s_barrier(); \
    __builtin_amdgcn_s_setprio(1); mm_phase<1, 1>(acc, av, bv); __builtin_amdgcn_s_setprio(0); \
    if (pf_) { asm volatile("s_waitcnt vmcnt(8)"); } \
    else     { asm volatile("s_waitcnt vmcnt(0)"); } \
    __builtin_amdgcn_s_barrier(); \
  } while (0)

  for (int kt = 0; kt < NT; kt += 2) {
    KTILE(0, kt);
    KTILE(1, kt + 1);
  }
#undef KTILE
#undef RDA
#undef RDB01
#undef RDB23

  // ---- epilogue: raw dot stores, fn innermost (line-adjacent) ----
  int cr = lane >> 4, cc = lane & 15;
  #pragma unroll
  for (int fm = 0; fm < 8; ++fm) {
    int rb = bm0 + wm * 128 + fm * 16 + cr * 4;
    #pragma unroll
    for (int j = 0; j < 4; ++j) {
      size_t rowo = (size_t)(rb + j) * N + bn0 + wn * 64 + cc;
      #pragma unroll
      for (int fn = 0; fn < 4; ++fn) {
        dot[rowo + fn * 16] = acc[fm][fn][j];
      }
    }
  }
}

// ---------- K3: MLR transcendentals + ball-lift + logmap0, in place ----------
__global__ void k_mlr_final(float* __restrict__ io, const float* __restrict__ cx2,
                            const float* __restrict__ invomc, const float* __restrict__ zn2,
                            const float* __restrict__ chb, const float* __restrict__ shb,
                            int N) {
  int row = blockIdx.x, t = threadIdx.x;
  float4* ior = (float4*)(io + (size_t)row * N);
  const float4* ch4 = (const float4*)chb;
  const float4* sh4 = (const float4*)shb;
  const float4* z24 = (const float4*)zn2;
  float c2 = cx2[row], inv = invomc[row];
  float opc = 1.f + c2;
  float y[4][4];
  float s = 0.f;
  #pragma unroll
  for (int i = 0; i < 4; ++i) {
    int idx = t + (i << 8);
    float4 d = ior[idx], ch = ch4[idx], sh = sh4[idx], z2 = z24[idx];
    float dq[4] = {d.x, d.y, d.z, d.w};
    float chq[4] = {ch.x, ch.y, ch.z, ch.w};
    float shq[4] = {sh.x, sh.y, sh.z, sh.w};
    float zq[4] = {z2.x, z2.y, z2.z, z2.w};
    #pragma unroll
    for (int q = 0; q < 4; ++q) {
      float num = 2.f * dq[q] * chq[q] - opc * shq[q];
      float mlr = zq[q] * asinhf(num * inv);
      float yy = sinhf(mlr);
      y[i][q] = yy;
      s += yy * yy;
    }
  }
  float ny2 = block_reduce_sum_256(s);
  float ny = sqrtf(ny2);
  float sfac = 1.f / (1.f + sqrtf(1.f + ny2));  // lift: y_ball = sfac*y
  float w = sfac * ny;
  float nw = fmaxf(w, EPSF);
  float tt = fminf(nw, 1.f - EPSF);
  float coef = atanhf(tt) * sfac / nw;
  #pragma unroll
  for (int i = 0; i < 4; ++i) {
    int idx = t + (i << 8);
    float4 o;
    o.x = coef * y[i][0]; o.y = coef * y[i][1];
    o.z = coef * y[i][2]; o.w = coef * y[i][3];
    ior[idx] = o;
  }
}

extern "C" void kernel_launch(void* const* d_in, const int* in_sizes, int n_in,
                              void* d_out, int out_size, void* d_ws, size_t ws_size,
                              hipStream_t stream) {
  const float* x    = (const float*)d_in[0];
  const float* z    = (const float*)d_in[1];
  const float* bias = (const float*)d_in[2];
  float* out = (float*)d_out;

  int N = in_sizes[2];           // DOUT = 4096
  int K = in_sizes[1] / N;       // DIN  = 4096
  int M = in_sizes[0] / K;       // B    = 8192

  char* ws = (char*)d_ws;
  size_t o = 0;
  __hip_bfloat16* h  = (__hip_bfloat16*)(ws + o); o += (size_t)M * K * 2;
  __hip_bfloat16* zt = (__hip_bfloat16*)(ws + o); o += (size_t)N * K * 2;
  float* cx2    = (float*)(ws + o); o += (size_t)M * 4;
  float* invomc = (float*)(ws + o); o += (size_t)M * 4;
  float* part   = (float*)(ws + o); o += (size_t)32 * N * 4;
  float* zn2    = (float*)(ws + o); o += (size_t)N * 4;
  float* invzn  = (float*)(ws + o); o += (size_t)N * 4;
  float* chb    = (float*)(ws + o); o += (size_t)N * 4;
  float* shb    = (float*)(ws + o); o += (size_t)N * 4;

  const int NCH = 32;
  k_expmap<<<M, 256, 0, stream>>>(x, h, cx2, invomc, K);
  k_colsq<<<dim3(N / 1024, NCH), 256, 0, stream>>>(z, part, K, N, K / NCH);
  k_colfin<<<N / 256, 256, 0, stream>>>(part, bias, zn2, invzn, chb, shb, N, NCH);
  k_zunitT<<<dim3(N / 32, K / 32), dim3(32, 8), 0, stream>>>(z, invzn, zt, K, N);
  int grid = (M / 256) * (N / 256);
  k_gemm_dot<<<grid, 512, 0, stream>>>(h, zt, out, M, N, K);
  k_mlr_final<<<M, 256, 0, stream>>>(out, cx2, invomc, zn2, chb, shb, N);
}

// Round 8
// 416.828 us; speedup vs baseline: 1.7259x; 1.3896x over previous
//
#include <hip/hip_runtime.h>
#include <hip/hip_bf16.h>
#include <math.h>

#define EPSF 1e-5f
#define LOG2E 1.4426950408889634f
#define LN2 0.6931471805599453f

typedef __attribute__((ext_vector_type(4))) float f32x4;
typedef __attribute__((ext_vector_type(8))) short s16x8;

__device__ __forceinline__ float hw_exp2(float x) { return __builtin_amdgcn_exp2f(x); }
__device__ __forceinline__ float hw_log2(float x) { return __builtin_amdgcn_logf(x); }
__device__ __forceinline__ float fast_rcp(float x) { return __builtin_amdgcn_rcpf(x); }

// ---------- block reduction (256 threads = 4 waves) ----------
__device__ __forceinline__ float block_reduce_sum_256(float s) {
  #pragma unroll
  for (int o = 32; o > 0; o >>= 1) s += __shfl_xor(s, o, 64);
  __shared__ float red[4];
  int lane = threadIdx.x & 63, wid = threadIdx.x >> 6;
  if (lane == 0) red[wid] = s;
  __syncthreads();
  return red[0] + red[1] + red[2] + red[3];
}

__device__ __forceinline__ unsigned short f2bu(float f) {
  __hip_bfloat16 b = __float2bfloat16(f);
  return __builtin_bit_cast(unsigned short, b);
}

// ---------- K0: h = expmap0(x) as bf16; cx2, 1/(1-cx2) per row (float4) ----------
__global__ void k_expmap(const float* __restrict__ x, __hip_bfloat16* __restrict__ h,
                         float* __restrict__ cx2, float* __restrict__ invomc, int K) {
  int row = blockIdx.x, t = threadIdx.x;
  const float4* xr = (const float4*)(x + (size_t)row * K);
  float4 v[4];
  float s = 0.f;
  #pragma unroll
  for (int i = 0; i < 4; ++i) {
    v[i] = xr[t + (i << 8)];
    s += v[i].x * v[i].x + v[i].y * v[i].y + v[i].z * v[i].z + v[i].w * v[i].w;
  }
  float nsq = block_reduce_sum_256(s);
  float n = fmaxf(sqrtf(nsq), EPSF);
  // tanh(n) = 1 - 2/(exp2(2n*log2e)+1), hw exp2 + rcp
  float e2 = hw_exp2(2.f * LOG2E * n);
  float th = 1.f - 2.f * fast_rcp(e2 + 1.f);
  float sc = th * fast_rcp(n);        // tanh(n)/n, rc = 1
  float hn2 = sc * sc * nsq;          // ||h||^2
  float c2 = fminf(hn2, 1.f - EPSF);
  if (t == 0) { cx2[row] = c2; invomc[row] = 1.f / (1.f - c2); }
  ushort4* hr = (ushort4*)(h + (size_t)row * K);
  #pragma unroll
  for (int i = 0; i < 4; ++i) {
    ushort4 o;
    o.x = f2bu(sc * v[i].x); o.y = f2bu(sc * v[i].y);
    o.z = f2bu(sc * v[i].z); o.w = f2bu(sc * v[i].w);
    hr[t + (i << 8)] = o;
  }
}

// ---------- K1a: partial column sum-of-squares of z (float4, deterministic) ----------
__global__ void k_colsq(const float* __restrict__ z, float* __restrict__ part,
                        int K, int N, int rows_per_chunk) {
  int c4 = blockIdx.x * 256 + threadIdx.x;    // float4 column index
  int r0 = blockIdx.y * rows_per_chunk;
  const float4* z4 = (const float4*)z;
  int n4 = N >> 2;
  float4 a = {0.f, 0.f, 0.f, 0.f};
  for (int r = r0; r < r0 + rows_per_chunk; ++r) {
    float4 v = z4[(size_t)r * n4 + c4];
    a.x += v.x * v.x; a.y += v.y * v.y; a.z += v.z * v.z; a.w += v.w * v.w;
  }
  ((float4*)part)[(size_t)blockIdx.y * n4 + c4] = a;
}

// ---------- K1b: finalize per-column scalars ----------
__global__ void k_colfin(const float* __restrict__ part, const float* __restrict__ bias,
                         float* __restrict__ zn2, float* __restrict__ invzn,
                         float* __restrict__ ch, float* __restrict__ sh,
                         int N, int nchunk) {
  int c = blockIdx.x * 256 + threadIdx.x;
  float s = 0.f;
  for (int i = 0; i < nchunk; ++i) s += part[(size_t)i * N + c];
  float zn = fmaxf(sqrtf(s), EPSF);
  zn2[c] = 2.f * zn;
  invzn[c] = 1.f / zn;
  float d = 2.f * bias[c];
  // cosh/sinh via hw exp2 (|d| tiny; rcp error negligible vs threshold)
  float ep = hw_exp2(LOG2E * d);
  float em = fast_rcp(ep);
  ch[c] = 0.5f * (ep + em);
  sh[c] = 0.5f * (ep - em);
}

// ---------- K1c: z_unit^T (N x K) bf16, LDS tile transpose ----------
__global__ void k_zunitT(const float* __restrict__ z, const float* __restrict__ invzn,
                         __hip_bfloat16* __restrict__ zt, int K, int N) {
  __shared__ float tile[32][33];
  int tx = threadIdx.x, ty = threadIdx.y;   // (32,8)
  int c0 = blockIdx.x * 32, r0 = blockIdx.y * 32;
  float inv = invzn[c0 + tx];
  #pragma unroll
  for (int i = 0; i < 4; ++i)
    tile[ty + i * 8][tx] = z[(size_t)(r0 + ty + i * 8) * N + c0 + tx] * inv;
  __syncthreads();
  #pragma unroll
  for (int i = 0; i < 4; ++i)
    zt[(size_t)(c0 + ty + i * 8) * K + r0 + tx] = __float2bfloat16(tile[tx][ty + i * 8]);
}

// ---------- MFMA phase helper (compile-time quadrant) ----------
template<int MQ, int NQ>
__device__ __forceinline__ void mm_phase(f32x4 (&acc)[8][4], const s16x8 (&av)[4][2],
                                         const s16x8 (&bv)[4][2]) {
  #pragma unroll
  for (int i = 0; i < 4; ++i) {
    #pragma unroll
    for (int jn = 0; jn < 2; ++jn) {
      acc[MQ * 4 + i][NQ * 2 + jn] = __builtin_amdgcn_mfma_f32_16x16x32_bf16(
          av[i][0], bv[NQ * 2 + jn][0], acc[MQ * 4 + i][NQ * 2 + jn], 0, 0, 0);
      acc[MQ * 4 + i][NQ * 2 + jn] = __builtin_amdgcn_mfma_f32_16x16x32_bf16(
          av[i][1], bv[NQ * 2 + jn][1], acc[MQ * 4 + i][NQ * 2 + jn], 0, 0, 0);
    }
  }
}

// force a (uniform) pointer into SGPRs so global_load_lds uses saddr form
__device__ __forceinline__ const char* RFL64(const char* p) {
  unsigned long long b = (unsigned long long)p;
  unsigned int lo = __builtin_amdgcn_readfirstlane((unsigned int)b);
  unsigned int hi = __builtin_amdgcn_readfirstlane((unsigned int)(b >> 32));
  return (const char*)(((unsigned long long)hi << 32) | lo);
}

// ---------- K2: 256x256 8-phase bf16 MFMA GEMM -> raw dot products ----------
// (identical to R6 — MfmaUtil 46%, 265 us)
__global__ __launch_bounds__(512, 1) void k_gemm_dot(
    const __hip_bfloat16* __restrict__ A,   // h: M x K
    const __hip_bfloat16* __restrict__ Bt,  // z_unit^T: N x K
    float* __restrict__ dot, int M, int N, int K) {
  __shared__ __align__(16) char smem[131072];
  const int K2 = K * 2;
  int tid = threadIdx.x, lane = tid & 63, wid = tid >> 6;
  int wm = wid >> 2, wn = wid & 3;

  // bijective XCD swizzle (gridDim.x % 8 == 0 here: 512 blocks)
  int bid = blockIdx.x;
  int cpx = gridDim.x >> 3;
  int swz = (bid & 7) * cpx + (bid >> 3);
  int nbx = N >> 8;
  int bx = swz % nbx, by = swz / nbx;
  int bm0 = by * 256, bn0 = bx * 256;

  // ---- staging: per-lane 32-bit offsets (inverse-swizzled source) ----
  int rr = (tid >> 2) & 15;
  int cbyte = ((tid & 3) * 16) ^ ((rr & 8) << 2);
  int kb = ((tid >> 6) & 1) * 64 + cbyte;          // k-byte within tile [0,128)
  int r0 = ((tid >> 7) << 4) + rr;                 // row (j=0); j=1 adds 64
  unsigned int off0 = (unsigned int)(r0 * K2 + kb);
  unsigned int off1 = off0 + (unsigned int)(64 * K2);
  int ldsW = wid * 1024;                           // linear dest (lane*16 implicit)

  const char* aPan0 = (const char*)A + (size_t)bm0 * K2;
  const char* aPan1 = aPan0 + (size_t)128 * K2;
  const char* bPan0 = (const char*)Bt + (size_t)bn0 * K2;
  const char* bPan1 = bPan0 + (size_t)128 * K2;

  auto STAGE = [&](const char* base, int ldsBase) {
    __builtin_amdgcn_global_load_lds(
        (const __attribute__((address_space(1))) unsigned int*)(base + off0),
        (__attribute__((address_space(3))) unsigned int*)(smem + ldsBase + ldsW), 16, 0, 0);
    __builtin_amdgcn_global_load_lds(
        (const __attribute__((address_space(1))) unsigned int*)(base + off1),
        (__attribute__((address_space(3))) unsigned int*)(smem + ldsBase + ldsW + 8192), 16, 0, 0);
  };

  // ---- LDS read bases (swizzled) ----
  int labase = (lane & 15) * 64 + (((lane >> 4) * 16) ^ ((lane & 8) << 2));
  const char* pA0 = smem + wm * 16384 + labase;
  const char* pA1 = pA0 + 65536;
  const char* pB0 = smem + 32768 + (wn >> 1) * 16384 + (wn & 1) * 8192 + labase;
  const char* pB1 = pB0 + 65536;

  s16x8 av[4][2], bv[4][2];
  f32x4 acc[8][4] = {};

#define RDA(D, MQ) do { const char* p_ = ((D) ? pA1 : pA0); \
    _Pragma("unroll") for (int i_ = 0; i_ < 4; ++i_) { \
      av[i_][0] = *(const s16x8*)(p_ + (MQ) * 8192 + i_ * 2048); \
      av[i_][1] = *(const s16x8*)(p_ + (MQ) * 8192 + i_ * 2048 + 1024); } } while (0)
#define RDB01(D) do { const char* p_ = ((D) ? pB1 : pB0); \
    _Pragma("unroll") for (int f_ = 0; f_ < 2; ++f_) { \
      bv[f_][0] = *(const s16x8*)(p_ + f_ * 2048); \
      bv[f_][1] = *(const s16x8*)(p_ + f_ * 2048 + 1024); } } while (0)
#define RDB23(D) do { const char* p_ = ((D) ? pB1 : pB0); \
    _Pragma("unroll") for (int f_ = 2; f_ < 4; ++f_) { \
      bv[f_][0] = *(const s16x8*)(p_ + f_ * 2048); \
      bv[f_][1] = *(const s16x8*)(p_ + f_ * 2048 + 1024); } } while (0)

  int NT = K >> 6;   // K-tiles of 64 (assumed even)

  // ---- prologue: stage tile0 (8 loads) + tile1 (8 loads) ----
  {
    const char* a0 = RFL64(aPan0); const char* a1 = RFL64(aPan1);
    const char* b0 = RFL64(bPan0); const char* b1 = RFL64(bPan1);
    STAGE(b0, 32768); STAGE(b1, 49152); STAGE(a0, 0); STAGE(a1, 16384);
  }
  if (NT > 1) {
    const char* a0 = RFL64(aPan0 + 128); const char* a1 = RFL64(aPan1 + 128);
    const char* b0 = RFL64(bPan0 + 128); const char* b1 = RFL64(bPan1 + 128);
    STAGE(b0, 65536 + 32768); STAGE(b1, 65536 + 49152);
    STAGE(a0, 65536); STAGE(a1, 65536 + 16384);
    asm volatile("s_waitcnt vmcnt(8)");
  } else {
    asm volatile("s_waitcnt vmcnt(0)");
  }
  __builtin_amdgcn_s_barrier();

#define KTILE(D, KT) do { \
    bool pf_ = ((KT) + 2 < NT); \
    int kOff2_ = ((KT) + 2) << 7; \
    const char* aB0_ = RFL64(aPan0 + kOff2_); \
    const char* aB1_ = RFL64(aPan1 + kOff2_); \
    const char* bB0_ = RFL64(bPan0 + kOff2_); \
    const char* bB1_ = RFL64(bPan1 + kOff2_); \
    /* p0: (0,0) */ \
    RDA(D, 0); RDB01(D); \
    __builtin_amdgcn_s_barrier(); \
    asm volatile("s_waitcnt lgkmcnt(0)"); \
    __builtin_amdgcn_s_setprio(1); mm_phase<0, 0>(acc, av, bv); __builtin_amdgcn_s_setprio(0); \
    __builtin_amdgcn_s_barrier(); \
    /* p1: (0,1) */ \
    RDB23(D); \
    __builtin_amdgcn_s_barrier(); \
    asm volatile("s_waitcnt lgkmcnt(0)"); \
    __builtin_amdgcn_s_setprio(1); mm_phase<0, 1>(acc, av, bv); __builtin_amdgcn_s_setprio(0); \
    __builtin_amdgcn_s_barrier(); \
    /* p2: (1,0); stage B(kt+2) */ \
    RDA(D, 1); \
    if (pf_) { STAGE(bB0_, (D) * 65536 + 32768); STAGE(bB1_, (D) * 65536 + 49152); } \
    __builtin_amdgcn_s_barrier(); \
    asm volatile("s_waitcnt lgkmcnt(0)"); \
    __builtin_amdgcn_s_setprio(1); mm_phase<1, 0>(acc, av, bv); __builtin_amdgcn_s_setprio(0); \
    __builtin_amdgcn_s_barrier(); \
    /* p3: (1,1); stage A(kt+2) */ \
    if (pf_) { STAGE(aB0_, (D) * 65536); STAGE(aB1_, (D) * 65536 + 16384); } \
    __builtin_amdgcn_s_barrier(); \
    __builtin_amdgcn_s_setprio(1); mm_phase<1, 1>(acc, av, bv); __builtin_amdgcn_s_setprio(0); \
    if (pf_) { asm volatile("s_waitcnt vmcnt(8)"); } \
    else     { asm volatile("s_waitcnt vmcnt(0)"); } \
    __builtin_amdgcn_s_barrier(); \
  } while (0)

  for (int kt = 0; kt < NT; kt += 2) {
    KTILE(0, kt);
    KTILE(1, kt + 1);
  }
#undef KTILE
#undef RDA
#undef RDB01
#undef RDB23

  // ---- epilogue: raw dot stores, fn innermost (line-adjacent) ----
  int cr = lane >> 4, cc = lane & 15;
  #pragma unroll
  for (int fm = 0; fm < 8; ++fm) {
    int rb = bm0 + wm * 128 + fm * 16 + cr * 4;
    #pragma unroll
    for (int j = 0; j < 4; ++j) {
      size_t rowo = (size_t)(rb + j) * N + bn0 + wn * 64 + cc;
      #pragma unroll
      for (int fn = 0; fn < 4; ++fn) {
        dot[rowo + fn * 16] = acc[fm][fn][j];
      }
    }
  }
}

// ---------- K3: MLR + ball-lift + logmap0, hw-transcendental, in place ----------
// y = sinh(s*asinh(u)) = 0.5*(w^s - w^(-s)), w = u + sqrt(u^2+1), s = zn2[c].
// w^s = exp2(s*log2(w)). All TRANS-pipe single instructions.
__global__ void k_mlr_final(float* __restrict__ io, const float* __restrict__ cx2,
                            const float* __restrict__ invomc, const float* __restrict__ zn2,
                            const float* __restrict__ chb, const float* __restrict__ shb,
                            int N) {
  int row = blockIdx.x, t = threadIdx.x;
  float4* ior = (float4*)(io + (size_t)row * N);
  const float4* ch4 = (const float4*)chb;
  const float4* sh4 = (const float4*)shb;
  const float4* z24 = (const float4*)zn2;
  float c2 = cx2[row], inv = invomc[row];
  float opc = 1.f + c2;
  float y[4][4];
  float s = 0.f;
  #pragma unroll
  for (int i = 0; i < 4; ++i) {
    int idx = t + (i << 8);
    float4 d = ior[idx], ch = ch4[idx], sh = sh4[idx], z2 = z24[idx];
    float dq[4] = {d.x, d.y, d.z, d.w};
    float chq[4] = {ch.x, ch.y, ch.z, ch.w};
    float shq[4] = {sh.x, sh.y, sh.z, sh.w};
    float zq[4] = {z2.x, z2.y, z2.z, z2.w};
    #pragma unroll
    for (int q = 0; q < 4; ++q) {
      float u = (2.f * dq[q] * chq[q] - opc * shq[q]) * inv;
      float w = u + sqrtf(fmaf(u, u, 1.f));
      float p = hw_log2(w);
      float tq = zq[q] * p;
      float ep = hw_exp2(tq);
      float em = hw_exp2(-tq);
      float yy = 0.5f * (ep - em);
      y[i][q] = yy;
      s += yy * yy;
    }
  }
  float ny2 = block_reduce_sum_256(s);
  float ny = sqrtf(ny2);
  float sfac = fast_rcp(1.f + sqrtf(1.f + ny2));  // lift: y_ball = sfac*y
  float w = sfac * ny;
  float nw = fmaxf(w, EPSF);
  float tt = fminf(nw, 1.f - EPSF);
  // atanh(tt) = 0.5*ln((1+tt)/(1-tt))
  float la = 0.5f * LN2 * hw_log2((1.f + tt) * fast_rcp(1.f - tt));
  float coef = la * sfac * fast_rcp(nw);
  #pragma unroll
  for (int i = 0; i < 4; ++i) {
    int idx = t + (i << 8);
    float4 o;
    o.x = coef * y[i][0]; o.y = coef * y[i][1];
    o.z = coef * y[i][2]; o.w = coef * y[i][3];
    ior[idx] = o;
  }
}

extern "C" void kernel_launch(void* const* d_in, const int* in_sizes, int n_in,
                              void* d_out, int out_size, void* d_ws, size_t ws_size,
                              hipStream_t stream) {
  const float* x    = (const float*)d_in[0];
  const float* z    = (const float*)d_in[1];
  const float* bias = (const float*)d_in[2];
  float* out = (float*)d_out;

  int N = in_sizes[2];           // DOUT = 4096
  int K = in_sizes[1] / N;       // DIN  = 4096
  int M = in_sizes[0] / K;       // B    = 8192

  char* ws = (char*)d_ws;
  size_t o = 0;
  __hip_bfloat16* h  = (__hip_bfloat16*)(ws + o); o += (size_t)M * K * 2;
  __hip_bfloat16* zt = (__hip_bfloat16*)(ws + o); o += (size_t)N * K * 2;
  float* cx2    = (float*)(ws + o); o += (size_t)M * 4;
  float* invomc = (float*)(ws + o); o += (size_t)M * 4;
  float* part   = (float*)(ws + o); o += (size_t)32 * N * 4;
  float* zn2    = (float*)(ws + o); o += (size_t)N * 4;
  float* invzn  = (float*)(ws + o); o += (size_t)N * 4;
  float* chb    = (float*)(ws + o); o += (size_t)N * 4;
  float* shb    = (float*)(ws + o); o += (size_t)N * 4;

  const int NCH = 32;
  k_expmap<<<M, 256, 0, stream>>>(x, h, cx2, invomc, K);
  k_colsq<<<dim3(N / 1024, NCH), 256, 0, stream>>>(z, part, K, N, K / NCH);
  k_colfin<<<N / 256, 256, 0, stream>>>(part, bias, zn2, invzn, chb, shb, N, NCH);
  k_zunitT<<<dim3(N / 32, K / 32), dim3(32, 8), 0, stream>>>(z, invzn, zt, K, N);
  int grid = (M / 256) * (N / 256);
  k_gemm_dot<<<grid, 512, 0, stream>>>(h, zt, out, M, N, K);
  k_mlr_final<<<M, 256, 0, stream>>>(out, cx2, invomc, zn2, chb, shb, N);
}